// Round 12
// baseline (185.361 us; speedup 1.0000x reference)
//
#include <hip/hip_runtime.h>
#include <hip/hip_fp16.h>

// LBP semantic dependency, channel-difference form, base-2 domain.
//   d'(x,p) = sp(x+p) - sp(x);  db[a,u] = edge + sum_{v!=a,u} sum_t d'-terms
// All db quantities in units of ln2. tp = e^p quantized fp16.
// R20 = R17 skeleton + VECTORIZED LDS SWEEPS (4u x 8v register tiles):
//   Budget that finally closes: per-slice 31us (R17==R18) ~= sweep LDS-pipe
//   time: 2 scalar u16 ds_reads + 1 E-read per term = ~7200 wave-instrs/CU
//   x 5.8cy on the ONE per-CU LDS pipe = 25-35us. Explains all nulls: R16
//   batching cut stalls not instrs; R17 diet cut trans not LDS; R18/R19
//   occupancy moves can't help a per-CU-pipe saturation. Restaging is dead
//   (R15/R19: FETCH 2x, serial latency). Fix: per-thread 4u x 8v tile ->
//   A 8x ds_read_b64 + B 8x b64 + E 2x b128 = 18 instrs / 32 terms (5x cut).
//   STR 162->164 (rows 328 B = 0 mod 8) so b64s are aligned.
//   scr shrunk to 800 floats; reduces use 5-slot staged RMW (LDS = 163,200B).

#define S    160
#define S2   25600            // 160*160
#define S3   4096000          // 160^3 (per-n slab, elements)
#define STR  164              // LDS slab row stride in halves (8B-aligned rows)
#define C2E  1.4426950408889634f

__device__ __forceinline__ float fexp2(float x) { return __builtin_amdgcn_exp2f(x); }
__device__ __forceinline__ float flog2(float x) { return __builtin_amdgcn_logf(x); }
__device__ __forceinline__ float cdb(float x) {
    return fminf(fmaxf(x, -45.f), 45.f);  // saturated beyond ~30 either way
}
__device__ __forceinline__ float sp2t(float tp) { return flog2(1.f + tp); }
__device__ __forceinline__ float Ff(float x, float tp) {
    float tx = fexp2(x);
    return flog2(1.f + tx * tp) - flog2(1.f + tx);
}
__device__ __forceinline__ const float* selT(int t, const float* a,
                                             const float* b, const float* c) {
    return (t == 0) ? a : (t == 1) ? b : c;
}
__device__ __forceinline__ float hlo(unsigned u) {
    __half2 h = *(__half2*)&u; return __low2float(h);
}
__device__ __forceinline__ float hhi(unsigned u) {
    __half2 h = *(__half2*)&u; return __high2float(h);
}
// extract float i (0..3) of a b64 (4 halves) register pair; i compile-time
#define HEXT(av, i) ((i)==0 ? hlo((av).x) : (i)==1 ? hhi((av).x) : \
                     (i)==2 ? hlo((av).y) : hhi((av).y))

// One block per slice (n,a). 960 threads (15 waves), 163,200B LDS, 1 blk/CU,
// grid 320 (2 rounds).
__global__ __launch_bounds__(960)
void k_fused(const float* __restrict__ s_sib, const float* __restrict__ s_cop,
             const float* __restrict__ s_grd, const float* __restrict__ s_edge,
             float* __restrict__ outp)
{
    int slice = blockIdx.x;           // 0..319
    int a = slice % S, n = slice / S;
    int tid = threadIdx.x;
    int u4 = tid % 40, r = tid / 40;  // staging: v = r+24i; sweeps: tile (u4, r)

    __shared__ __align__(16) __half tp3[3 * S * STR];   // 157,440 B
    __shared__ __align__(16) float  scr[800];           //   3,200 B
    __shared__ __align__(16) float  db1s[S];
    __shared__ __align__(16) float  db2s[S];
    __shared__ __align__(16) float  E1[S];
    __shared__ __align__(16) float  E2[S];              //   2,560 B

    // ---- staging (R17): all 960 threads; v = r+24i, product ph1 partials
    float4 acc = make_float4(0.f, 0.f, 0.f, 0.f);
    float edg = 0.f;
    if (tid < S) edg = s_edge[(long)n * S2 + tid * S + a] * C2E;
    #pragma unroll
    for (int t = 0; t < 3; ++t) {
        const float* g = selT(t, s_sib, s_cop, s_grd)
                       + (long)n * S3 + (long)a * S + u4 * 4;
        float4 pv[7];
        #pragma unroll
        for (int i = 0; i < 6; ++i)
            pv[i] = *(const float4*)(g + (long)(r + 24 * i) * S2);
        if (r < 16) pv[6] = *(const float4*)(g + (long)(r + 144) * S2);
        float4 P = make_float4(1.f, 1.f, 1.f, 1.f);
        #pragma unroll
        for (int i = 0; i < 7; ++i) {
            if (i == 6 && r >= 16) break;
            int v = r + 24 * i;
            float t0 = fexp2(pv[i].x * C2E), t1 = fexp2(pv[i].y * C2E);
            float t2 = fexp2(pv[i].z * C2E), t3 = fexp2(pv[i].w * C2E);
            P.x = __builtin_fmaf(P.x, t0, P.x);
            P.y = __builtin_fmaf(P.y, t1, P.y);
            P.z = __builtin_fmaf(P.z, t2, P.z);
            P.w = __builtin_fmaf(P.w, t3, P.w);
            __half* b = &tp3[t * (S * STR) + v * STR + u4 * 4];
            *(__half2*)(b)     = __floats2half2_rn(t0, t1);
            *(__half2*)(b + 2) = __floats2half2_rn(t2, t3);
        }
        acc.x += flog2(P.x); acc.y += flog2(P.y);
        acc.z += flog2(P.z); acc.w += flog2(P.w);
    }
    // ---- ph1 reduce: 24 r-groups -> 5 slots (write + 4 staged RMW)
    float4* scr4 = (float4*)scr;
    if (r < 5) scr4[r * 40 + u4] = acc;
    __syncthreads();
    if (r >= 5 && r < 10) {
        float4 o = scr4[(r - 5) * 40 + u4];
        o.x += acc.x; o.y += acc.y; o.z += acc.z; o.w += acc.w;
        scr4[(r - 5) * 40 + u4] = o;
    }
    __syncthreads();
    if (r >= 10 && r < 15) {
        float4 o = scr4[(r - 10) * 40 + u4];
        o.x += acc.x; o.y += acc.y; o.z += acc.z; o.w += acc.w;
        scr4[(r - 10) * 40 + u4] = o;
    }
    __syncthreads();
    if (r >= 15 && r < 20) {
        float4 o = scr4[(r - 15) * 40 + u4];
        o.x += acc.x; o.y += acc.y; o.z += acc.z; o.w += acc.w;
        scr4[(r - 15) * 40 + u4] = o;
    }
    __syncthreads();
    if (r >= 20) {
        float4 o = scr4[(r - 20) * 40 + u4];
        o.x += acc.x; o.y += acc.y; o.z += acc.z; o.w += acc.w;
        scr4[(r - 20) * 40 + u4] = o;
    }
    __syncthreads();
    // ---- db1 + E1 (exclusions from quantized slab)
    if (tid < S) {
        int u = tid;
        float s = 0.f;
        #pragma unroll
        for (int g2 = 0; g2 < 5; ++g2) s += scr[(g2 * 40 + (u >> 2)) * 4 + (u & 3)];
        float rr = edg + s - 480.f;
        #pragma unroll
        for (int t = 0; t < 3; ++t) {
            const __half* sl = &tp3[t * (S * STR)];
            float tpa = __half2float(sl[a * STR + u]);
            rr -= (sp2t(tpa) - 1.f);
            if (u != a) {
                float tpu = __half2float(sl[u * STR + u]);
                rr -= (sp2t(tpu) - 1.f);
            }
        }
        db1s[u] = rr;
        E1[u] = fexp2(cdb(rr) + 1.f);
    }
    __syncthreads();

    // ---- d2 sweep: 4u x 8v tiles, 800 active threads (r<20)
    const bool act = (r < 20);
    const int u0 = u4 * 4, v0 = r * 8;
    float4 ac2 = make_float4(0.f, 0.f, 0.f, 0.f);
    if (act) {
        #pragma unroll
        for (int t = 0; t < 3; ++t) {
            const __half* sl = &tp3[t * (S * STR)];
            uint2 avr[8];
            #pragma unroll
            for (int j = 0; j < 8; ++j)
                avr[j] = *(const uint2*)&sl[(v0 + j) * STR + u0];
            uint2 b0[4], b1[4];
            #pragma unroll
            for (int i = 0; i < 4; ++i) {
                b0[i] = *(const uint2*)&sl[(u0 + i) * STR + v0];
                b1[i] = *(const uint2*)&sl[(u0 + i) * STR + v0 + 4];
            }
            float Ev[8];
            *(float4*)&Ev[0] = *(const float4*)&E1[v0];
            *(float4*)&Ev[4] = *(const float4*)&E1[v0 + 4];
            #pragma unroll
            for (int i = 0; i < 4; ++i) {
                float tB[8];
                tB[0] = hlo(b0[i].x); tB[1] = hhi(b0[i].x);
                tB[2] = hlo(b0[i].y); tB[3] = hhi(b0[i].y);
                tB[4] = hlo(b1[i].x); tB[5] = hhi(b1[i].x);
                tB[6] = hlo(b1[i].y); tB[7] = hhi(b1[i].y);
                float s = 0.f;
                #pragma unroll
                for (int jp = 0; jp < 4; ++jp) {
                    float tA0 = HEXT(avr[2 * jp], i);
                    float tA1 = HEXT(avr[2 * jp + 1], i);
                    float B10 = 1.f + tB[2 * jp], B11 = 1.f + tB[2 * jp + 1];
                    float nm0 = __builtin_fmaf(Ev[2 * jp], tA0, B10);
                    float nm1 = __builtin_fmaf(Ev[2 * jp + 1], tA1, B11);
                    float dn0 = B10 + Ev[2 * jp], dn1 = B11 + Ev[2 * jp + 1];
                    s += flog2(nm0 * nm1) - flog2(dn0 * dn1);
                }
                if (i == 0) ac2.x += s; else if (i == 1) ac2.y += s;
                else if (i == 2) ac2.z += s; else ac2.w += s;
            }
        }
    }
    // reduce 20 v-groups -> 5 slots
    if (act && r < 5) scr4[r * 40 + u4] = ac2;
    __syncthreads();
    if (act && r >= 5 && r < 10) {
        float4 o = scr4[(r - 5) * 40 + u4];
        o.x += ac2.x; o.y += ac2.y; o.z += ac2.z; o.w += ac2.w;
        scr4[(r - 5) * 40 + u4] = o;
    }
    __syncthreads();
    if (act && r >= 10 && r < 15) {
        float4 o = scr4[(r - 10) * 40 + u4];
        o.x += ac2.x; o.y += ac2.y; o.z += ac2.z; o.w += ac2.w;
        scr4[(r - 10) * 40 + u4] = o;
    }
    __syncthreads();
    if (act && r >= 15) {
        float4 o = scr4[(r - 15) * 40 + u4];
        o.x += ac2.x; o.y += ac2.y; o.z += ac2.z; o.w += ac2.w;
        scr4[(r - 15) * 40 + u4] = o;
    }
    __syncthreads();
    // ---- db2 (inline di2) + E2
    if (tid < S) {
        int u = tid;
        float sw = 0.f;
        #pragma unroll
        for (int g2 = 0; g2 < 5; ++g2) sw += scr[(g2 * 40 + (u >> 2)) * 4 + (u & 3)];
        float db1a1 = cdb(db1s[a]) + 1.f;
        float db1u1 = cdb(db1s[u]) + 1.f;
        float sum = 0.f;
        #pragma unroll
        for (int t = 0; t < 3; ++t) {
            const __half* sl = &tp3[t * (S * STR)];
            float tpa  = __half2float(sl[a * STR + u]);
            float tpba = __half2float(sl[u * STR + a]);
            sum += Ff(db1a1 - sp2t(tpba), tpa);           // C2(v=a)
            if (u != a) {
                float tpu = __half2float(sl[u * STR + u]);
                sum += Ff(db1u1 - sp2t(tpu), tpu);        // C2(v=u)
            }
        }
        float d2v = edg - sum + sw;
        db2s[u] = d2v;
        E2[u] = fexp2(cdb(d2v));
    }
    __syncthreads();

    // ---- d3 sweep: same tiling
    float4 ac3 = make_float4(0.f, 0.f, 0.f, 0.f);
    float E1u[4];
    *(float4*)E1u = *(const float4*)&E1[u0];
    if (act) {
        #pragma unroll
        for (int t = 0; t < 3; ++t) {
            const __half* sl = &tp3[t * (S * STR)];
            uint2 avr[8];
            #pragma unroll
            for (int j = 0; j < 8; ++j)
                avr[j] = *(const uint2*)&sl[(v0 + j) * STR + u0];
            uint2 b0[4], b1[4];
            #pragma unroll
            for (int i = 0; i < 4; ++i) {
                b0[i] = *(const uint2*)&sl[(u0 + i) * STR + v0];
                b1[i] = *(const uint2*)&sl[(u0 + i) * STR + v0 + 4];
            }
            float Ev[8];
            *(float4*)&Ev[0] = *(const float4*)&E2[v0];
            *(float4*)&Ev[4] = *(const float4*)&E2[v0 + 4];
            #pragma unroll
            for (int i = 0; i < 4; ++i) {
                float tB[8];
                tB[0] = hlo(b0[i].x); tB[1] = hhi(b0[i].x);
                tB[2] = hlo(b0[i].y); tB[3] = hhi(b0[i].y);
                tB[4] = hlo(b1[i].x); tB[5] = hhi(b1[i].x);
                tB[6] = hlo(b1[i].y); tB[7] = hhi(b1[i].y);
                float e1i = E1u[i];
                float s = 0.f;
                #pragma unroll
                for (int j = 0; j < 8; ++j) {
                    float tA = HEXT(avr[j], i);
                    float A1 = 1.f + tA;
                    float q  = A1 + e1i;
                    float rr = __builtin_fmaf(e1i, tB[j], A1);
                    float p  = Ev[j] * q;
                    float nm = __builtin_fmaf(p, tA, rr);
                    float dn = rr + p;
                    s += flog2(nm) - flog2(dn);
                }
                if (i == 0) ac3.x += s; else if (i == 1) ac3.y += s;
                else if (i == 2) ac3.z += s; else ac3.w += s;
            }
        }
    }
    if (act && r < 5) scr4[r * 40 + u4] = ac3;
    __syncthreads();
    if (act && r >= 5 && r < 10) {
        float4 o = scr4[(r - 5) * 40 + u4];
        o.x += ac3.x; o.y += ac3.y; o.z += ac3.z; o.w += ac3.w;
        scr4[(r - 5) * 40 + u4] = o;
    }
    __syncthreads();
    if (act && r >= 10 && r < 15) {
        float4 o = scr4[(r - 10) * 40 + u4];
        o.x += ac3.x; o.y += ac3.y; o.z += ac3.z; o.w += ac3.w;
        scr4[(r - 10) * 40 + u4] = o;
    }
    __syncthreads();
    if (act && r >= 15) {
        float4 o = scr4[(r - 15) * 40 + u4];
        o.x += ac3.x; o.y += ac3.y; o.z += ac3.z; o.w += ac3.w;
        scr4[(r - 15) * 40 + u4] = o;
    }
    __syncthreads();
    // ---- di3 + output
    if (tid < S) {
        int u = tid;
        float sw = 0.f;
        #pragma unroll
        for (int g2 = 0; g2 < 5; ++g2) sw += scr[(g2 * 40 + (u >> 2)) * 4 + (u & 3)];
        float db1u1 = cdb(db1s[u]) + 1.f;
        float db2a = cdb(db2s[a]);
        float db2u = cdb(db2s[u]);
        float sum = 0.f;
        #pragma unroll
        for (int t = 0; t < 3; ++t) {
            const __half* sl = &tp3[t * (S * STR)];
            float tpa  = __half2float(sl[a * STR + u]);
            float tpba = __half2float(sl[u * STR + a]);
            float d2vu = Ff(db1u1 - sp2t(tpa), tpba);
            sum += Ff(db2a - d2vu, tpa);                  // C3(v=a)
            if (u != a) {
                float tpu = __half2float(sl[u * STR + u]);
                float d2  = Ff(db1u1 - sp2t(tpu), tpu);
                sum += Ff(db2u - d2, tpu);                // C3(v=u)
            }
        }
        float s = edg - sum + sw;
        float sc  = fminf(fmaxf(s, -60.f), 60.f);  // avoid exp2 overflow
        float tsg = fexp2(-sc);
        float rr  = __fdividef(1.f, 1.f + tsg);
        long ob = ((long)(n * S + u) * S + a) * 2;
        *(float2*)(outp + ob) = make_float2(tsg * rr, rr);
    }
}

extern "C" void kernel_launch(void* const* d_in, const int* in_sizes, int n_in,
                              void* d_out, int out_size, void* d_ws, size_t ws_size,
                              hipStream_t stream) {
    const float* s_edge = (const float*)d_in[0];
    const float* s_sib  = (const float*)d_in[1];
    const float* s_cop  = (const float*)d_in[2];
    const float* s_grd  = (const float*)d_in[3];
    float* outp = (float*)d_out;
    (void)d_ws; (void)ws_size;          // workspace unused (no poison fills)

    k_fused<<<320, 960, 0, stream>>>(s_sib, s_cop, s_grd, s_edge, outp);
}